// Round 7
// baseline (13303.217 us; speedup 1.0000x reference)
//
#include <hip/hip_runtime.h>

// ---------------------------------------------------------------------------
// mLSTM epitope/antigen model, MI355X fp16-MFMA, round 7.
//
// R7 vs R6 (5.61 ms): PERSISTENT kernel for all 153 steps (was 306
// dispatches). 256 blocks x 256 thr (fits by capacity even if 8 blocks/CU
// -> co-resident, DIY grid barrier safe). Monotone-counter grid barrier
// (agent-scope atomics, s_sleep spin). Static t-invariant work map:
//   XCD x owns colq==x mod 8 (WhS slice L2-affine) and ct==x mod 8;
//   each wave owns the same (colq,rtp) unit every step
//   => LSTM c-state lives in VGPRs across all 153 steps (no global c).
// K-loop bodies identical to R6 (branch-free, fragment-swizzled, reg-direct).
// ---------------------------------------------------------------------------

typedef _Float16 f16;
typedef _Float16 half8 __attribute__((ext_vector_type(8)));
typedef float f32x4 __attribute__((ext_vector_type(4)));

#define H_    1900
#define HP    1920
#define NKA   60     // K-chunks for h/WmhS (1920/32)
#define NKB   61     // K-chunks for m/WhS (1952/32)
#define NKF   120    // K-chunks for fc1 (3840/32)
#define NR    512
#define TT    153
#define TE    25
#define EMB_  10
#define FCN   384
#define NBLK  256    // persistent grid size

__device__ __forceinline__ float sigm(float x) {
  float p = __expf(-fabsf(x));
  float r = 1.f / (1.f + p);
  return x >= 0.f ? r : 1.f - r;
}
__device__ __forceinline__ float tanh_(float x) {
  float p = __expf(-2.f * fabsf(x));
  float r = (1.f - p) / (1.f + p);
  return x >= 0.f ? r : -r;
}

// ---------------- prep ----------------

__global__ void k_norms(const float* __restrict__ wh, const float* __restrict__ wx,
                        const float* __restrict__ wmh, const float* __restrict__ wmx,
                        const float* __restrict__ gh, const float* __restrict__ gx,
                        const float* __restrict__ gmh, const float* __restrict__ gmx,
                        float* __restrict__ inv_wh, float* __restrict__ inv_wx,
                        float* __restrict__ inv_wmh, float* __restrict__ inv_wmx) {
  int tid = blockIdx.x * 256 + threadIdx.x;
  if (tid < 7600) {
    float s = 0.f;
    for (int k = 0; k < H_; k++) { float v = wh[(size_t)k * 7600 + tid]; s += v * v; }
    inv_wh[tid] = gh[tid] * rsqrtf(fmaxf(s, 1e-12f));
  } else if (tid < 15200) {
    int n = tid - 7600; float s = 0.f;
    for (int e = 0; e < EMB_; e++) { float v = wx[(size_t)e * 7600 + n]; s += v * v; }
    inv_wx[n] = gx[n] * rsqrtf(fmaxf(s, 1e-12f));
  } else if (tid < 17100) {
    int n = tid - 15200; float s = 0.f;
    for (int k = 0; k < H_; k++) { float v = wmh[(size_t)k * H_ + n]; s += v * v; }
    inv_wmh[n] = gmh[n] * rsqrtf(fmaxf(s, 1e-12f));
  } else if (tid < 19000) {
    int n = tid - 17100; float s = 0.f;
    for (int e = 0; e < EMB_; e++) { float v = wmx[(size_t)e * H_ + n]; s += v * v; }
    inv_wmx[n] = gmx[n] * rsqrtf(fmaxf(s, 1e-12f));
  }
}

__global__ void k_wmhS(const float* __restrict__ wmh, const float* __restrict__ inv,
                       f16* __restrict__ WmhS) {
  int i = blockIdx.x * 256 + threadIdx.x;
  if (i >= 1920 * 1920) return;
  int n = i % 1920, k = i / 1920;
  float v = (n < H_ && k < H_) ? wmh[(size_t)k * H_ + n] * inv[n] : 0.f;
  int c = n >> 4, nl = n & 15, kb = k >> 5, kl = k & 31;
  WmhS[(((size_t)c * NKA + kb) * 512) + (nl + 16 * (kl >> 3)) * 8 + (kl & 7)] = (f16)v;
}

__global__ void k_whS(const float* __restrict__ wh, const float* __restrict__ wx,
                      const float* __restrict__ bias,
                      const float* __restrict__ inv_wh, const float* __restrict__ inv_wx,
                      f16* __restrict__ WhS) {
  int i = blockIdx.x * 256 + threadIdx.x;
  if (i >= 7600 * 1952) return;
  int col = i % 7600, k = i / 7600;
  float v = 0.f;
  if (k < H_)                        v = wh[(size_t)k * 7600 + col] * inv_wh[col];
  else if (k >= HP && k < HP + EMB_) v = wx[(size_t)(k - HP) * 7600 + col] * inv_wx[col];
  else if (k == HP + EMB_)           v = bias[col];
  int g = col / H_, n = col % H_;
  int q = n >> 4, nl = n & 15, kb = k >> 5, kl = k & 31;
  WhS[(((size_t)(q * 4 + g) * NKB + kb) * 512) + (nl + 16 * (kl >> 3)) * 8 + (kl & 7)] = (f16)v;
}

__global__ void k_wmxT(const float* __restrict__ wmx, const float* __restrict__ inv_wmx,
                       f16* __restrict__ wmxT) {
  int i = blockIdx.x * 256 + threadIdx.x;
  if (i >= HP * 32) return;
  int n = i >> 5, k = i & 31;
  float v = (k < EMB_ && n < H_) ? wmx[(size_t)k * H_ + n] * inv_wmx[n] : 0.f;
  wmxT[i] = (f16)v;
}

__global__ void k_lens(const int* __restrict__ ex, const int* __restrict__ lx,
                       const int* __restrict__ rx, int* __restrict__ sel) {
  int s = threadIdx.x;
  int el = 0; for (int i = 0; i < 25; i++) el += (ex[s * 25 + i] != 26);
  int ll = 0; for (int i = 0; i < 64; i++) ll += (lx[s * 64 + i] != 26);
  int rl = 0; for (int i = 0; i < 64; i++) rl += (rx[s * 64 + i] != 26);
  ll = ll < 1 ? 1 : ll;  rl = rl < 1 ? 1 : rl;
  int tl = el + ll + rl;
  int ti = tl - 1; ti = ti < 0 ? 0 : (ti > 152 ? 152 : ti);
  int ei = el - 1; ei = ei < 0 ? 0 : (ei > 24 ? 24 : ei);
  sel[s] = ti; sel[256 + s] = ei;
}

__global__ void k_init(f16* __restrict__ h0, f16* __restrict__ h1, int* __restrict__ bar) {
  int i = blockIdx.x * 256 + threadIdx.x;
  if (i < NR * HP) { h0[i] = (f16)0.f; h1[i] = (f16)0.f; }
  if (i < 16) bar[i] = 0;
}

__global__ void k_xe16(const int* __restrict__ totx, const int* __restrict__ epix,
                       const float* __restrict__ embed, f16* __restrict__ xe16) {
  int i = blockIdx.x * blockDim.x + threadIdx.x;
  if (i >= TT * NR) return;
  int t = i / NR, r = i % NR;
  int tok = -1;
  if (r < 256) tok = totx[r * TT + t];
  else if (t < TE) tok = epix[(r - 256) * TE + t];
  f16* o = xe16 + (size_t)i * 32;
  #pragma unroll
  for (int e = 0; e < EMB_; e++) o[e] = (f16)(tok >= 0 ? embed[tok * EMB_ + e] : 0.f);
  o[10] = (f16)1.f;
  #pragma unroll
  for (int e = 11; e < 32; e++) o[e] = (f16)0.f;
}

// ---------------- persistent recurrence ----------------

__device__ __forceinline__ void gridbar(int* bar, int target) {
  __syncthreads();
  if (threadIdx.x == 0) {
    __threadfence();
    __hip_atomic_fetch_add(bar, 1, __ATOMIC_RELEASE, __HIP_MEMORY_SCOPE_AGENT);
    while (__hip_atomic_load(bar, __ATOMIC_RELAXED, __HIP_MEMORY_SCOPE_AGENT) < target)
      __builtin_amdgcn_s_sleep(8);
    __threadfence();
  }
  __syncthreads();
}

// Phase A body: wave = 16 rows x 64 cols, m = (xe @ wmxT) ⊙ (h @ WmhS)
__device__ __forceinline__ void bodyA(
    const f16* __restrict__ hS, const f16* __restrict__ WmhS,
    const f16* __restrict__ xe_t, const f16* __restrict__ wmxT,
    f16* __restrict__ mS, int ct, int rtile, int lane) {
  const int r0 = rtile * 16;
  const int l16 = lane & 15, l4 = lane >> 4;
  const f16* Abase = hS   + (size_t)rtile * NKA * 512 + lane * 8;
  const f16* Bbase = WmhS + (size_t)(ct * 4) * NKA * 512 + lane * 8;

  f32x4 xm[4];
  {
    half8 xa = *(const half8*)(xe_t + (size_t)(r0 + l16) * 32 + l4 * 8);
    #pragma unroll
    for (int cb = 0; cb < 4; cb++) {
      half8 xb = *(const half8*)(wmxT + (size_t)(ct * 64 + cb * 16 + l16) * 32 + l4 * 8);
      f32x4 z = {0.f, 0.f, 0.f, 0.f};
      xm[cb] = __builtin_amdgcn_mfma_f32_16x16x32_f16(xa, xb, z, 0, 0, 0);
    }
  }

  half8 fa0, fa1, fa2, fa3;
  half8 fb0[4], fb1[4], fb2[4], fb3[4];
  f32x4 acc[4];
  #pragma unroll
  for (int cb = 0; cb < 4; cb++) { f32x4 z = {0.f, 0.f, 0.f, 0.f}; acc[cb] = z; }

#define LDA_A(d, kb)  d = *(const half8*)(Abase + (size_t)(kb) * 512)
#define LDB_A(d, kb)  { _Pragma("unroll") for (int cb = 0; cb < 4; cb++) \
    d[cb] = *(const half8*)(Bbase + ((size_t)cb * NKA + (kb)) * 512); }
#define MMA_A(fa, fb) { _Pragma("unroll") for (int cb = 0; cb < 4; cb++) \
    acc[cb] = __builtin_amdgcn_mfma_f32_16x16x32_f16(fa, fb[cb], acc[cb], 0, 0, 0); }

  LDA_A(fa0, 0); LDB_A(fb0, 0);
  LDA_A(fa1, 1); LDB_A(fb1, 1);
  LDA_A(fa2, 2); LDB_A(fb2, 2);
  for (int base = 0; base < 56; base += 4) {
    LDA_A(fa3, base + 3); LDB_A(fb3, base + 3);
    MMA_A(fa0, fb0);
    LDA_A(fa0, base + 4); LDB_A(fb0, base + 4);
    MMA_A(fa1, fb1);
    LDA_A(fa1, base + 5); LDB_A(fb1, base + 5);
    MMA_A(fa2, fb2);
    LDA_A(fa2, base + 6); LDB_A(fb2, base + 6);
    MMA_A(fa3, fb3);
  }
  LDA_A(fa3, 59); LDB_A(fb3, 59);
  MMA_A(fa0, fb0);
  MMA_A(fa1, fb1);
  MMA_A(fa2, fb2);
  MMA_A(fa3, fb3);
#undef LDA_A
#undef LDB_A
#undef MMA_A

  const int q4 = lane >> 4, c16 = lane & 15;
  #pragma unroll
  for (int cb = 0; cb < 4; cb++) {
    int kb = ct * 2 + (cb >> 1);
    int klane = (cb & 1) * 16 + c16;
    int lf = (klane >> 3) * 16;
    int sub = c16 & 7;
    f16* dst = mS + ((size_t)rtile * NKB + kb) * 512 + sub;
    #pragma unroll
    for (int q = 0; q < 4; q++) {
      int rl = q4 * 4 + q;
      dst[(rl + lf) * 8] = (f16)(acc[cb][q] * xm[cb][q]);
    }
  }
  if (ct == 0) {
    f16* dst = mS + ((size_t)rtile * NKB + 60) * 512 + lane * 8;
    *(half8*)dst = *(const half8*)(xe_t + (size_t)(r0 + l16) * 32 + l4 * 8);
  }
}

// Phase B body: wave = 32 rows x (16 cols x 4 gates); c-state in VGPRs.
__device__ __forceinline__ void bodyB(
    const f16* __restrict__ mS, const f16* __restrict__ WhS,
    f16* __restrict__ houtS, float* __restrict__ selH,
    const int* __restrict__ sel, int t, int colq, int rtp, int lane,
    f32x4 (&creg)[2]) {
  const int rt0 = rtp * 2;
  const int r0 = rt0 * 16;

  const f16* Abase = mS  + (size_t)rt0 * NKB * 512 + lane * 8;
  const f16* Bbase = WhS + (size_t)(colq * 4) * NKB * 512 + lane * 8;

  half8 fa0[2], fa1[2], fa2[2], fa3[2];
  half8 fb0[4], fb1[4], fb2[4], fb3[4];
  f32x4 acc[2][4];
  #pragma unroll
  for (int a = 0; a < 2; a++)
    #pragma unroll
    for (int b = 0; b < 4; b++) { f32x4 z = {0.f, 0.f, 0.f, 0.f}; acc[a][b] = z; }

#define LDA_B(d, kb)  { _Pragma("unroll") for (int rf = 0; rf < 2; rf++) \
    d[rf] = *(const half8*)(Abase + ((size_t)rf * NKB + (kb)) * 512); }
#define LDB_B(d, kb)  { _Pragma("unroll") for (int gg = 0; gg < 4; gg++) \
    d[gg] = *(const half8*)(Bbase + ((size_t)gg * NKB + (kb)) * 512); }
#define MMA_B(fa, fb) { _Pragma("unroll") for (int rf = 0; rf < 2; rf++) \
    { _Pragma("unroll") for (int gg = 0; gg < 4; gg++) \
      acc[rf][gg] = __builtin_amdgcn_mfma_f32_16x16x32_f16(fa[rf], fb[gg], acc[rf][gg], 0, 0, 0); } }

  LDA_B(fa0, 0); LDB_B(fb0, 0);
  LDA_B(fa1, 1); LDB_B(fb1, 1);
  LDA_B(fa2, 2); LDB_B(fb2, 2);
  for (int base = 0; base < 56; base += 4) {
    LDA_B(fa3, base + 3); LDB_B(fb3, base + 3);
    MMA_B(fa0, fb0);
    LDA_B(fa0, base + 4); LDB_B(fb0, base + 4);
    MMA_B(fa1, fb1);
    LDA_B(fa1, base + 5); LDB_B(fb1, base + 5);
    MMA_B(fa2, fb2);
    LDA_B(fa2, base + 6); LDB_B(fb2, base + 6);
    MMA_B(fa3, fb3);
  }
  LDA_B(fa3, 59); LDB_B(fb3, 59);
  MMA_B(fa0, fb0);   // 56
  LDA_B(fa0, 60); LDB_B(fb0, 60);
  MMA_B(fa1, fb1);   // 57
  MMA_B(fa2, fb2);   // 58
  MMA_B(fa3, fb3);   // 59
  MMA_B(fa0, fb0);   // 60
#undef LDA_B
#undef LDB_B
#undef MMA_B

  const int q4 = lane >> 4, c16 = lane & 15;
  const int j = colq * 16 + c16;
  const bool valid = j < H_;
  const int kbh = colq >> 1;
  const int lfh = ((((colq & 1) * 16 + c16) >> 3)) * 16;
  const int subh = c16 & 7;
  #pragma unroll
  for (int rf = 0; rf < 2; rf++) {
    f16* hdst = houtS + ((size_t)(rt0 + rf) * NKA + kbh) * 512 + subh;
    #pragma unroll
    for (int q = 0; q < 4; q++) {
      int rl = q4 * 4 + q;
      int row = r0 + rf * 16 + rl;
      if (valid) {
        float cold = creg[rf][q];
        float iz = acc[rf][0][q], fz = acc[rf][1][q];
        float oz = acc[rf][2][q], uz = acc[rf][3][q];
        float cn = sigm(fz) * cold + sigm(iz) * tanh_(uz);
        float hv = sigm(oz) * tanh_(cn);
        creg[rf][q] = cn;
        hdst[(rl + lfh) * 8] = (f16)hv;
        if (t == sel[row]) selH[(size_t)row * HP + j] = hv;
      }
    }
  }
}

__global__ __launch_bounds__(256)
void k_recur(const f16* __restrict__ WmhS, const f16* __restrict__ WhS,
             const f16* __restrict__ xe16, const f16* __restrict__ wmxT,
             f16* __restrict__ h0S, f16* __restrict__ h1S,
             f16* __restrict__ mS, float* __restrict__ selH,
             const int* __restrict__ sel, int* __restrict__ bar) {
  const int b = blockIdx.x;
  const int x = b & 7;            // XCD-stable slice id
  const int lb = b >> 3;          // 0..31
  const int wid = threadIdx.x >> 6, lane = threadIdx.x & 63;
  const int lw = lb * 4 + wid;    // 0..127 within slice

  // phase A map: cti 0..3 (ct = x+8*cti), rtA 0..31
  const int cti = lw & 3, rtA = lw >> 2;
  const int nct = (x < 6) ? 4 : 3;
  const int ct = x + 8 * cti;
  const bool actA = (cti < nct);
  // phase B map: colqi 0..15 (colq = x+8*colqi), rtpB 0..7
  const int colqi = lw & 15, rtpB = lw >> 4;
  const int ncq = (x < 7) ? 15 : 14;
  const int colq = x + 8 * colqi;
  const bool actB = (colqi < ncq);

  f32x4 cA[2], cB[2];
  #pragma unroll
  for (int i = 0; i < 2; i++) { f32x4 z = {0.f, 0.f, 0.f, 0.f}; cA[i] = z; cB[i] = z; }

  int barid = 0;
  for (int t = 0; t < TT; t++) {
    const f16* hin = (t & 1) ? h1S : h0S;
    f16*       ho  = (t & 1) ? h0S : h1S;
    const f16* xe_t = xe16 + (size_t)t * NR * 32;

    if (actA && (rtA < 16 || t < TE))
      bodyA(hin, WmhS, xe_t, wmxT, mS, ct, rtA, lane);
    barid++; gridbar(bar, barid * NBLK);

    if (actB) {
      bodyB(mS, WhS, ho, selH, sel, t, colq, rtpB, lane, cA);
      if (t < TE)
        bodyB(mS, WhS, ho, selH, sel, t, colq, rtpB + 8, lane, cB);
    }
    barid++; gridbar(bar, barid * NBLK);
  }
}

// ---------------- classifier ----------------

__global__ void k_xqS(const float* __restrict__ selH, const float* __restrict__ g1,
                      const float* __restrict__ be1, const float* __restrict__ mu1,
                      const float* __restrict__ var1, f16* __restrict__ xqS) {
  int i = blockIdx.x * 256 + threadIdx.x;
  if (i >= 256 * 3840) return;
  int k = i % 3840, s = i / 3840;
  float v = 0.f; bool have = false;
  if (k < H_)            { v = selH[(size_t)s * HP + k]; have = true; }
  else if (k < 2 * H_)   { v = selH[(size_t)(256 + s) * HP + (k - H_)]; have = true; }
  float q = 0.f;
  if (have) {
    float lr = v < 0.f ? 0.3f * v : v;
    q = (lr - mu1[k]) * rsqrtf(var1[k] + 1e-3f) * g1[k] + be1[k];
  }
  int rtile = s >> 4, sl = s & 15, kb = k >> 5, kl = k & 31;
  xqS[(((size_t)rtile * NKF + kb) * 512) + (sl + 16 * (kl >> 3)) * 8 + (kl & 7)] = (f16)q;
}

__global__ void k_w1S(const float* __restrict__ W1, f16* __restrict__ W1S) {
  int i = blockIdx.x * 256 + threadIdx.x;
  if (i >= 384 * 3840) return;
  int col = i % 384, k = i / 384;
  float v = (col < 380 && k < 2 * H_) ? W1[(size_t)k * 380 + col] : 0.f;
  int cg = col >> 4, nl = col & 15, kb = k >> 5, kl = k & 31;
  W1S[(((size_t)cg * NKF + kb) * 512) + (nl + 16 * (kl >> 3)) * 8 + (kl & 7)] = (f16)v;
}

__global__ __launch_bounds__(256)
void k_fc1(const f16* __restrict__ xqS, const f16* __restrict__ W1S,
           const float* __restrict__ b1, float* __restrict__ z1) {
  const int lane = threadIdx.x & 63, wid = threadIdx.x >> 6;
  const int ct = blockIdx.x % 6, rg = blockIdx.x / 6;
  const int rtile = rg * 4 + wid;
  const int r0 = rtile * 16;

  const f16* Abase = xqS + (size_t)rtile * NKF * 512 + lane * 8;
  const f16* Bbase = W1S + (size_t)(ct * 4) * NKF * 512 + lane * 8;

  half8 fa0, fa1, fa2, fa3;
  half8 fb0[4], fb1[4], fb2[4], fb3[4];
  f32x4 acc[4];
  #pragma unroll
  for (int cb = 0; cb < 4; cb++) { f32x4 z = {0.f, 0.f, 0.f, 0.f}; acc[cb] = z; }

#define LDA_F(d, kb)  d = *(const half8*)(Abase + (size_t)(kb) * 512)
#define LDB_F(d, kb)  { _Pragma("unroll") for (int cb = 0; cb < 4; cb++) \
    d[cb] = *(const half8*)(Bbase + ((size_t)cb * NKF + (kb)) * 512); }
#define MMA_F(fa, fb) { _Pragma("unroll") for (int cb = 0; cb < 4; cb++) \
    acc[cb] = __builtin_amdgcn_mfma_f32_16x16x32_f16(fa, fb[cb], acc[cb], 0, 0, 0); }

  LDA_F(fa0, 0); LDB_F(fb0, 0);
  LDA_F(fa1, 1); LDB_F(fb1, 1);
  LDA_F(fa2, 2); LDB_F(fb2, 2);
  for (int base = 0; base < 116; base += 4) {
    LDA_F(fa3, base + 3); LDB_F(fb3, base + 3);
    MMA_F(fa0, fb0);
    LDA_F(fa0, base + 4); LDB_F(fb0, base + 4);
    MMA_F(fa1, fb1);
    LDA_F(fa1, base + 5); LDB_F(fb1, base + 5);
    MMA_F(fa2, fb2);
    LDA_F(fa2, base + 6); LDB_F(fb2, base + 6);
    MMA_F(fa3, fb3);
  }
  LDA_F(fa3, 119); LDB_F(fb3, 119);
  MMA_F(fa0, fb0);   // 116
  MMA_F(fa1, fb1);   // 117
  MMA_F(fa2, fb2);   // 118
  MMA_F(fa3, fb3);   // 119
#undef LDA_F
#undef LDB_F
#undef MMA_F

  const int q4 = lane >> 4, c16 = lane & 15;
  #pragma unroll
  for (int cb = 0; cb < 4; cb++)
    #pragma unroll
    for (int q = 0; q < 4; q++) {
      int row = r0 + q4 * 4 + q;
      int col = ct * 64 + cb * 16 + c16;
      float bias = (col < 380) ? b1[col] : 0.f;
      z1[(size_t)row * FCN + col] = acc[cb][q] + bias;
    }
}

__global__ void k_fc2(const float* __restrict__ z1, const float* __restrict__ g2,
                      const float* __restrict__ be2, const float* __restrict__ mu2,
                      const float* __restrict__ var2, const float* __restrict__ W2,
                      const float* __restrict__ b2, float* __restrict__ out) {
  int s = threadIdx.x;
  float a = 0.f;
  for (int jj = 0; jj < 380; jj++) {
    float v = z1[(size_t)s * FCN + jj];
    float lr = v < 0.f ? 0.3f * v : v;
    float q = (lr - mu2[jj]) * rsqrtf(var2[jj] + 1e-3f) * g2[jj] + be2[jj];
    a += q * W2[jj];
  }
  out[s] = a + b2[0];
}

// ---------------- host ----------------

extern "C" void kernel_launch(void* const* d_in, const int* in_sizes, int n_in,
                              void* d_out, int out_size, void* d_ws, size_t ws_size,
                              hipStream_t stream) {
  const int*   epix  = (const int*)d_in[0];
  const int*   lx    = (const int*)d_in[1];
  const int*   rx    = (const int*)d_in[2];
  const int*   totx  = (const int*)d_in[3];
  const float* embed = (const float*)d_in[4];
  const float* wx    = (const float*)d_in[5];
  const float* wh    = (const float*)d_in[6];
  const float* wmx   = (const float*)d_in[7];
  const float* wmh   = (const float*)d_in[8];
  const float* bb    = (const float*)d_in[9];
  const float* gx    = (const float*)d_in[10];
  const float* gh    = (const float*)d_in[11];
  const float* gmx   = (const float*)d_in[12];
  const float* gmh   = (const float*)d_in[13];
  const float* bn1g  = (const float*)d_in[14];
  const float* bn1b  = (const float*)d_in[15];
  const float* bn1m  = (const float*)d_in[16];
  const float* bn1v  = (const float*)d_in[17];
  const float* W1    = (const float*)d_in[18];
  const float* b1    = (const float*)d_in[19];
  const float* bn2g  = (const float*)d_in[20];
  const float* bn2b  = (const float*)d_in[21];
  const float* bn2m  = (const float*)d_in[22];
  const float* bn2v  = (const float*)d_in[23];
  const float* W2    = (const float*)d_in[24];
  const float* b2v   = (const float*)d_in[25];

  char* base = (char*)d_ws;
  size_t off = 0;
  auto alloc = [&](size_t n) { char* p = base + off; off = (off + n + 255) & ~(size_t)255; return p; };

  f16*   WmhS   = (f16*)  alloc((size_t)120 * NKA * 512 * 2);
  f16*   WhS    = (f16*)  alloc((size_t)119 * 4 * NKB * 512 * 2);
  f16*   wmxT   = (f16*)  alloc((size_t)HP * 32 * 2);
  f16*   xe16   = (f16*)  alloc((size_t)TT * NR * 32 * 2);
  f16*   h0S    = (f16*)  alloc((size_t)32 * NKA * 512 * 2);
  f16*   h1S    = (f16*)  alloc((size_t)32 * NKA * 512 * 2);
  f16*   mS     = (f16*)  alloc((size_t)32 * NKB * 512 * 2);
  float* selH   = (float*)alloc((size_t)NR * HP * 4);
  int*   sel    = (int*)  alloc((size_t)NR * 4);
  int*   bar    = (int*)  alloc(256);
  float* inv_wh = (float*)alloc(7600 * 4);
  float* inv_wx = (float*)alloc(7600 * 4);
  float* inv_wmh= (float*)alloc(1900 * 4);
  float* inv_wmx= (float*)alloc(1900 * 4);
  f16*   xqS    = (f16*)  alloc((size_t)16 * NKF * 512 * 2);
  f16*   W1S    = (f16*)  alloc((size_t)24 * NKF * 512 * 2);
  float* z1     = (float*)alloc((size_t)256 * FCN * 4);
  (void)in_sizes; (void)n_in; (void)out_size; (void)ws_size;

  hipLaunchKernelGGL(k_norms, dim3(75), dim3(256), 0, stream,
                     wh, wx, wmh, wmx, gh, gx, gmh, gmx, inv_wh, inv_wx, inv_wmh, inv_wmx);
  hipLaunchKernelGGL(k_wmhS, dim3((1920 * 1920 + 255) / 256), dim3(256), 0, stream,
                     wmh, inv_wmh, WmhS);
  hipLaunchKernelGGL(k_whS, dim3((7600 * 1952 + 255) / 256), dim3(256), 0, stream,
                     wh, wx, bb, inv_wh, inv_wx, WhS);
  hipLaunchKernelGGL(k_wmxT, dim3((HP * 32 + 255) / 256), dim3(256), 0, stream,
                     wmx, inv_wmx, wmxT);
  hipLaunchKernelGGL(k_lens, dim3(1), dim3(256), 0, stream, epix, lx, rx, sel);
  hipLaunchKernelGGL(k_init, dim3((NR * HP + 255) / 256), dim3(256), 0, stream,
                     h0S, h1S, bar);
  hipLaunchKernelGGL(k_xe16, dim3((TT * NR + 255) / 256), dim3(256), 0, stream,
                     totx, epix, embed, xe16);

  hipLaunchKernelGGL(k_recur, dim3(NBLK), dim3(256), 0, stream,
                     WmhS, WhS, xe16, wmxT, h0S, h1S, mS, selH, sel, bar);

  hipLaunchKernelGGL(k_xqS, dim3((256 * 3840 + 255) / 256), dim3(256), 0, stream,
                     selH, bn1g, bn1b, bn1m, bn1v, xqS);
  hipLaunchKernelGGL(k_w1S, dim3((384 * 3840 + 255) / 256), dim3(256), 0, stream, W1, W1S);
  hipLaunchKernelGGL(k_fc1, dim3(24), dim3(256), 0, stream, xqS, W1S, b1, z1);
  hipLaunchKernelGGL(k_fc2, dim3(1), dim3(256), 0, stream,
                     z1, bn2g, bn2b, bn2m, bn2v, W2, b2v, (float*)d_out);
}

// Round 8
// 8387.531 us; speedup vs baseline: 1.5861x; 1.5861x over previous
//
#include <hip/hip_runtime.h>

// ---------------------------------------------------------------------------
// mLSTM epitope/antigen model, MI355X fp16-MFMA, round 8.
//
// R8 vs R7 (13.3 ms; k_recur 13.0 ms, FETCH 4.4 GB @ 379 GB/s):
//  R7's per-step __threadfence() barriers invalidated every XCD L2 twice a
//  step -> whole 37 MB weight set re-streamed from L3 each step + fence-storm
//  throttled fabric. R8 is FENCE-FREE:
//   - m/h cross-XCD handoff: system-scope relaxed atomic stores (write-
//     through to coherence point) into 10-deep RING buffers (fresh address
//     per step -> no stale L2/L1 lines), consumers use plain cached loads.
//   - barrier: relaxed atomics + explicit vmcnt(0) drain before arrive.
//   - ONE acquire fence every 8 steps (ring 10 > 8 => slot reuse always
//     crosses a fence; guaranteed coherence). Weights stay L2-resident
//     between fences (~4.6 MB/step amortized refetch).
// ---------------------------------------------------------------------------

typedef _Float16 f16;
typedef _Float16 half8 __attribute__((ext_vector_type(8)));
typedef float f32x4 __attribute__((ext_vector_type(4)));

#define H_    1900
#define HP    1920
#define NKA   60     // K-chunks for h/WmhS (1920/32)
#define NKB   61     // K-chunks for m/WhS (1952/32)
#define NKF   120    // K-chunks for fc1 (3840/32)
#define NR    512
#define TT    153
#define TE    25
#define EMB_  10
#define FCN   384
#define NBLK  256
#define RING  10
#define MSLOT ((size_t)32 * NKB * 512)
#define HSLOT ((size_t)32 * NKA * 512)

__device__ __forceinline__ float sigm(float x) {
  float p = __expf(-fabsf(x));
  float r = 1.f / (1.f + p);
  return x >= 0.f ? r : 1.f - r;
}
__device__ __forceinline__ float tanh_(float x) {
  float p = __expf(-2.f * fabsf(x));
  float r = (1.f - p) / (1.f + p);
  return x >= 0.f ? r : -r;
}

// write-through (system-scope) scalar stores for cross-XCD data
__device__ __forceinline__ void st16(f16* p, f16 v) {
  unsigned short u = __builtin_bit_cast(unsigned short, v);
  __hip_atomic_store((unsigned short*)p, u, __ATOMIC_RELAXED,
                     __HIP_MEMORY_SCOPE_SYSTEM);
}
__device__ __forceinline__ void st32(unsigned int* p, unsigned int v) {
  __hip_atomic_store(p, v, __ATOMIC_RELAXED, __HIP_MEMORY_SCOPE_SYSTEM);
}

// ---------------- prep ----------------

__global__ void k_norms(const float* __restrict__ wh, const float* __restrict__ wx,
                        const float* __restrict__ wmh, const float* __restrict__ wmx,
                        const float* __restrict__ gh, const float* __restrict__ gx,
                        const float* __restrict__ gmh, const float* __restrict__ gmx,
                        float* __restrict__ inv_wh, float* __restrict__ inv_wx,
                        float* __restrict__ inv_wmh, float* __restrict__ inv_wmx) {
  int tid = blockIdx.x * 256 + threadIdx.x;
  if (tid < 7600) {
    float s = 0.f;
    for (int k = 0; k < H_; k++) { float v = wh[(size_t)k * 7600 + tid]; s += v * v; }
    inv_wh[tid] = gh[tid] * rsqrtf(fmaxf(s, 1e-12f));
  } else if (tid < 15200) {
    int n = tid - 7600; float s = 0.f;
    for (int e = 0; e < EMB_; e++) { float v = wx[(size_t)e * 7600 + n]; s += v * v; }
    inv_wx[n] = gx[n] * rsqrtf(fmaxf(s, 1e-12f));
  } else if (tid < 17100) {
    int n = tid - 15200; float s = 0.f;
    for (int k = 0; k < H_; k++) { float v = wmh[(size_t)k * H_ + n]; s += v * v; }
    inv_wmh[n] = gmh[n] * rsqrtf(fmaxf(s, 1e-12f));
  } else if (tid < 19000) {
    int n = tid - 17100; float s = 0.f;
    for (int e = 0; e < EMB_; e++) { float v = wmx[(size_t)e * H_ + n]; s += v * v; }
    inv_wmx[n] = gmx[n] * rsqrtf(fmaxf(s, 1e-12f));
  }
}

__global__ void k_wmhS(const float* __restrict__ wmh, const float* __restrict__ inv,
                       f16* __restrict__ WmhS) {
  int i = blockIdx.x * 256 + threadIdx.x;
  if (i >= 1920 * 1920) return;
  int n = i % 1920, k = i / 1920;
  float v = (n < H_ && k < H_) ? wmh[(size_t)k * H_ + n] * inv[n] : 0.f;
  int c = n >> 4, nl = n & 15, kb = k >> 5, kl = k & 31;
  WmhS[(((size_t)c * NKA + kb) * 512) + (nl + 16 * (kl >> 3)) * 8 + (kl & 7)] = (f16)v;
}

__global__ void k_whS(const float* __restrict__ wh, const float* __restrict__ wx,
                      const float* __restrict__ bias,
                      const float* __restrict__ inv_wh, const float* __restrict__ inv_wx,
                      f16* __restrict__ WhS) {
  int i = blockIdx.x * 256 + threadIdx.x;
  if (i >= 7600 * 1952) return;
  int col = i % 7600, k = i / 7600;
  float v = 0.f;
  if (k < H_)                        v = wh[(size_t)k * 7600 + col] * inv_wh[col];
  else if (k >= HP && k < HP + EMB_) v = wx[(size_t)(k - HP) * 7600 + col] * inv_wx[col];
  else if (k == HP + EMB_)           v = bias[col];
  int g = col / H_, n = col % H_;
  int q = n >> 4, nl = n & 15, kb = k >> 5, kl = k & 31;
  WhS[(((size_t)(q * 4 + g) * NKB + kb) * 512) + (nl + 16 * (kl >> 3)) * 8 + (kl & 7)] = (f16)v;
}

__global__ void k_wmxT(const float* __restrict__ wmx, const float* __restrict__ inv_wmx,
                       f16* __restrict__ wmxT) {
  int i = blockIdx.x * 256 + threadIdx.x;
  if (i >= HP * 32) return;
  int n = i >> 5, k = i & 31;
  float v = (k < EMB_ && n < H_) ? wmx[(size_t)k * H_ + n] * inv_wmx[n] : 0.f;
  wmxT[i] = (f16)v;
}

__global__ void k_lens(const int* __restrict__ ex, const int* __restrict__ lx,
                       const int* __restrict__ rx, int* __restrict__ sel) {
  int s = threadIdx.x;
  int el = 0; for (int i = 0; i < 25; i++) el += (ex[s * 25 + i] != 26);
  int ll = 0; for (int i = 0; i < 64; i++) ll += (lx[s * 64 + i] != 26);
  int rl = 0; for (int i = 0; i < 64; i++) rl += (rx[s * 64 + i] != 26);
  ll = ll < 1 ? 1 : ll;  rl = rl < 1 ? 1 : rl;
  int tl = el + ll + rl;
  int ti = tl - 1; ti = ti < 0 ? 0 : (ti > 152 ? 152 : ti);
  int ei = el - 1; ei = ei < 0 ? 0 : (ei > 24 ? 24 : ei);
  sel[s] = ti; sel[256 + s] = ei;
}

// zero h ring slot 9 (initial hidden state) + barrier counter
__global__ void k_init(f16* __restrict__ hR, int* __restrict__ bar) {
  int i = blockIdx.x * 256 + threadIdx.x;
  if (i < NR * HP) hR[9 * HSLOT + i] = (f16)0.f;
  if (i < 16) bar[i] = 0;
}

__global__ void k_xe16(const int* __restrict__ totx, const int* __restrict__ epix,
                       const float* __restrict__ embed, f16* __restrict__ xe16) {
  int i = blockIdx.x * blockDim.x + threadIdx.x;
  if (i >= TT * NR) return;
  int t = i / NR, r = i % NR;
  int tok = -1;
  if (r < 256) tok = totx[r * TT + t];
  else if (t < TE) tok = epix[(r - 256) * TE + t];
  f16* o = xe16 + (size_t)i * 32;
  #pragma unroll
  for (int e = 0; e < EMB_; e++) o[e] = (f16)(tok >= 0 ? embed[tok * EMB_ + e] : 0.f);
  o[10] = (f16)1.f;
  #pragma unroll
  for (int e = 11; e < 32; e++) o[e] = (f16)0.f;
}

// ---------------- persistent recurrence ----------------

__device__ __forceinline__ void gridbar(int* bar, int target, bool inv) {
  __builtin_amdgcn_s_waitcnt(0x0F70);  // vmcnt(0): this wave's stores at fabric
  __syncthreads();                     // all 4 waves drained
  if (threadIdx.x == 0) {
    __hip_atomic_fetch_add(bar, 1, __ATOMIC_RELAXED, __HIP_MEMORY_SCOPE_AGENT);
    while (__hip_atomic_load(bar, __ATOMIC_RELAXED, __HIP_MEMORY_SCOPE_AGENT) < target)
      __builtin_amdgcn_s_sleep(1);
    if (inv) __builtin_amdgcn_fence(__ATOMIC_ACQUIRE, "agent");  // rare: L1/L2 inv
  }
  __syncthreads();
}

// Phase A body: wave = 16 rows x 64 cols, m = (xe @ wmxT) ⊙ (h @ WmhS)
__device__ __forceinline__ void bodyA(
    const f16* __restrict__ hS, const f16* __restrict__ WmhS,
    const f16* __restrict__ xe_t, const f16* __restrict__ wmxT,
    f16* __restrict__ mS, int ct, int rtile, int lane) {
  const int r0 = rtile * 16;
  const int l16 = lane & 15, l4 = lane >> 4;
  const f16* Abase = hS   + (size_t)rtile * NKA * 512 + lane * 8;
  const f16* Bbase = WmhS + (size_t)(ct * 4) * NKA * 512 + lane * 8;

  f32x4 xm[4];
  {
    half8 xa = *(const half8*)(xe_t + (size_t)(r0 + l16) * 32 + l4 * 8);
    #pragma unroll
    for (int cb = 0; cb < 4; cb++) {
      half8 xb = *(const half8*)(wmxT + (size_t)(ct * 64 + cb * 16 + l16) * 32 + l4 * 8);
      f32x4 z = {0.f, 0.f, 0.f, 0.f};
      xm[cb] = __builtin_amdgcn_mfma_f32_16x16x32_f16(xa, xb, z, 0, 0, 0);
    }
  }

  half8 fa0, fa1, fa2, fa3;
  half8 fb0[4], fb1[4], fb2[4], fb3[4];
  f32x4 acc[4];
  #pragma unroll
  for (int cb = 0; cb < 4; cb++) { f32x4 z = {0.f, 0.f, 0.f, 0.f}; acc[cb] = z; }

#define LDA_A(d, kb)  d = *(const half8*)(Abase + (size_t)(kb) * 512)
#define LDB_A(d, kb)  { _Pragma("unroll") for (int cb = 0; cb < 4; cb++) \
    d[cb] = *(const half8*)(Bbase + ((size_t)cb * NKA + (kb)) * 512); }
#define MMA_A(fa, fb) { _Pragma("unroll") for (int cb = 0; cb < 4; cb++) \
    acc[cb] = __builtin_amdgcn_mfma_f32_16x16x32_f16(fa, fb[cb], acc[cb], 0, 0, 0); }

  LDA_A(fa0, 0); LDB_A(fb0, 0);
  LDA_A(fa1, 1); LDB_A(fb1, 1);
  LDA_A(fa2, 2); LDB_A(fb2, 2);
  for (int base = 0; base < 56; base += 4) {
    LDA_A(fa3, base + 3); LDB_A(fb3, base + 3);
    MMA_A(fa0, fb0);
    LDA_A(fa0, base + 4); LDB_A(fb0, base + 4);
    MMA_A(fa1, fb1);
    LDA_A(fa1, base + 5); LDB_A(fb1, base + 5);
    MMA_A(fa2, fb2);
    LDA_A(fa2, base + 6); LDB_A(fb2, base + 6);
    MMA_A(fa3, fb3);
  }
  LDA_A(fa3, 59); LDB_A(fb3, 59);
  MMA_A(fa0, fb0);
  MMA_A(fa1, fb1);
  MMA_A(fa2, fb2);
  MMA_A(fa3, fb3);
#undef LDA_A
#undef LDB_A
#undef MMA_A

  const int q4 = lane >> 4, c16 = lane & 15;
  #pragma unroll
  for (int cb = 0; cb < 4; cb++) {
    int kb = ct * 2 + (cb >> 1);
    int klane = (cb & 1) * 16 + c16;
    int lf = (klane >> 3) * 16;
    int sub = c16 & 7;
    f16* dst = mS + ((size_t)rtile * NKB + kb) * 512 + sub;
    #pragma unroll
    for (int q = 0; q < 4; q++) {
      int rl = q4 * 4 + q;
      st16(&dst[(rl + lf) * 8], (f16)(acc[cb][q] * xm[cb][q]));
    }
  }
  if (ct == 0) {  // K-extension chunk 60 = xe row (write-through dwords)
    unsigned int* dst = (unsigned int*)(mS + ((size_t)rtile * NKB + 60) * 512 + lane * 8);
    const unsigned int* src = (const unsigned int*)(xe_t + (size_t)(r0 + l16) * 32 + l4 * 8);
    #pragma unroll
    for (int w = 0; w < 4; w++) st32(dst + w, src[w]);
  }
}

// Phase B body: wave = 32 rows x (16 cols x 4 gates); c-state in VGPRs.
__device__ __forceinline__ void bodyB(
    const f16* __restrict__ mS, const f16* __restrict__ WhS,
    f16* __restrict__ houtS, float* __restrict__ selH,
    const int* __restrict__ sel, int t, int colq, int rtp, int lane,
    f32x4 (&creg)[2]) {
  const int rt0 = rtp * 2;
  const int r0 = rt0 * 16;

  const f16* Abase = mS  + (size_t)rt0 * NKB * 512 + lane * 8;
  const f16* Bbase = WhS + (size_t)(colq * 4) * NKB * 512 + lane * 8;

  half8 fa0[2], fa1[2], fa2[2], fa3[2];
  half8 fb0[4], fb1[4], fb2[4], fb3[4];
  f32x4 acc[2][4];
  #pragma unroll
  for (int a = 0; a < 2; a++)
    #pragma unroll
    for (int b = 0; b < 4; b++) { f32x4 z = {0.f, 0.f, 0.f, 0.f}; acc[a][b] = z; }

#define LDA_B(d, kb)  { _Pragma("unroll") for (int rf = 0; rf < 2; rf++) \
    d[rf] = *(const half8*)(Abase + ((size_t)rf * NKB + (kb)) * 512); }
#define LDB_B(d, kb)  { _Pragma("unroll") for (int gg = 0; gg < 4; gg++) \
    d[gg] = *(const half8*)(Bbase + ((size_t)gg * NKB + (kb)) * 512); }
#define MMA_B(fa, fb) { _Pragma("unroll") for (int rf = 0; rf < 2; rf++) \
    { _Pragma("unroll") for (int gg = 0; gg < 4; gg++) \
      acc[rf][gg] = __builtin_amdgcn_mfma_f32_16x16x32_f16(fa[rf], fb[gg], acc[rf][gg], 0, 0, 0); } }

  LDA_B(fa0, 0); LDB_B(fb0, 0);
  LDA_B(fa1, 1); LDB_B(fb1, 1);
  LDA_B(fa2, 2); LDB_B(fb2, 2);
  for (int base = 0; base < 56; base += 4) {
    LDA_B(fa3, base + 3); LDB_B(fb3, base + 3);
    MMA_B(fa0, fb0);
    LDA_B(fa0, base + 4); LDB_B(fb0, base + 4);
    MMA_B(fa1, fb1);
    LDA_B(fa1, base + 5); LDB_B(fb1, base + 5);
    MMA_B(fa2, fb2);
    LDA_B(fa2, base + 6); LDB_B(fb2, base + 6);
    MMA_B(fa3, fb3);
  }
  LDA_B(fa3, 59); LDB_B(fb3, 59);
  MMA_B(fa0, fb0);   // 56
  LDA_B(fa0, 60); LDB_B(fb0, 60);
  MMA_B(fa1, fb1);   // 57
  MMA_B(fa2, fb2);   // 58
  MMA_B(fa3, fb3);   // 59
  MMA_B(fa0, fb0);   // 60
#undef LDA_B
#undef LDB_B
#undef MMA_B

  const int q4 = lane >> 4, c16 = lane & 15;
  const int j = colq * 16 + c16;
  const bool valid = j < H_;
  const int kbh = colq >> 1;
  const int lfh = ((((colq & 1) * 16 + c16) >> 3)) * 16;
  const int subh = c16 & 7;
  #pragma unroll
  for (int rf = 0; rf < 2; rf++) {
    f16* hdst = houtS + ((size_t)(rt0 + rf) * NKA + kbh) * 512 + subh;
    #pragma unroll
    for (int q = 0; q < 4; q++) {
      int rl = q4 * 4 + q;
      int row = r0 + rf * 16 + rl;
      if (valid) {
        float cold = creg[rf][q];
        float iz = acc[rf][0][q], fz = acc[rf][1][q];
        float oz = acc[rf][2][q], uz = acc[rf][3][q];
        float cn = sigm(fz) * cold + sigm(iz) * tanh_(uz);
        float hv = sigm(oz) * tanh_(cn);
        creg[rf][q] = cn;
        st16(&hdst[(rl + lfh) * 8], (f16)hv);
        if (t == sel[row]) selH[(size_t)row * HP + j] = hv;
      }
    }
  }
}

__global__ __launch_bounds__(256)
void k_recur(const f16* __restrict__ WmhS, const f16* __restrict__ WhS,
             const f16* __restrict__ xe16, const f16* __restrict__ wmxT,
             f16* __restrict__ mR, f16* __restrict__ hR,
             float* __restrict__ selH, const int* __restrict__ sel,
             int* __restrict__ bar) {
  const int b = blockIdx.x;
  const int x = b & 7;
  const int lb = b >> 3;
  const int wid = threadIdx.x >> 6, lane = threadIdx.x & 63;
  const int lw = lb * 4 + wid;

  const int cti = lw & 3, rtA = lw >> 2;
  const int nct = (x < 6) ? 4 : 3;
  const int ct = x + 8 * cti;
  const bool actA = (cti < nct);
  const int colqi = lw & 15, rtpB = lw >> 4;
  const int ncq = (x < 7) ? 15 : 14;
  const int colq = x + 8 * colqi;
  const bool actB = (colqi < ncq);

  f32x4 cA[2], cB[2];
  #pragma unroll
  for (int i = 0; i < 2; i++) { f32x4 z = {0.f, 0.f, 0.f, 0.f}; cA[i] = z; cB[i] = z; }

  int barid = 0;
  for (int t = 0; t < TT; t++) {
    const f16* hin = hR + (size_t)((t + 9) % RING) * HSLOT;
    f16*       ho  = hR + (size_t)(t % RING) * HSLOT;
    f16*       mS  = mR + (size_t)(t % RING) * MSLOT;
    const f16* xe_t = xe16 + (size_t)t * NR * 32;
    const bool fence = ((t & 7) == 7);

    if (actA && (rtA < 16 || t < TE))
      bodyA(hin, WmhS, xe_t, wmxT, mS, ct, rtA, lane);
    barid++; gridbar(bar, barid * NBLK, false);

    if (actB) {
      bodyB(mS, WhS, ho, selH, sel, t, colq, rtpB, lane, cA);
      if (t < TE)
        bodyB(mS, WhS, ho, selH, sel, t, colq, rtpB + 8, lane, cB);
    }
    barid++; gridbar(bar, barid * NBLK, fence);
  }
}

// ---------------- classifier ----------------

__global__ void k_xqS(const float* __restrict__ selH, const float* __restrict__ g1,
                      const float* __restrict__ be1, const float* __restrict__ mu1,
                      const float* __restrict__ var1, f16* __restrict__ xqS) {
  int i = blockIdx.x * 256 + threadIdx.x;
  if (i >= 256 * 3840) return;
  int k = i % 3840, s = i / 3840;
  float v = 0.f; bool have = false;
  if (k < H_)            { v = selH[(size_t)s * HP + k]; have = true; }
  else if (k < 2 * H_)   { v = selH[(size_t)(256 + s) * HP + (k - H_)]; have = true; }
  float q = 0.f;
  if (have) {
    float lr = v < 0.f ? 0.3f * v : v;
    q = (lr - mu1[k]) * rsqrtf(var1[k] + 1e-3f) * g1[k] + be1[k];
  }
  int rtile = s >> 4, sl = s & 15, kb = k >> 5, kl = k & 31;
  xqS[(((size_t)rtile * NKF + kb) * 512) + (sl + 16 * (kl >> 3)) * 8 + (kl & 7)] = (f16)q;
}

__global__ void k_w1S(const float* __restrict__ W1, f16* __restrict__ W1S) {
  int i = blockIdx.x * 256 + threadIdx.x;
  if (i >= 384 * 3840) return;
  int col = i % 384, k = i / 384;
  float v = (col < 380 && k < 2 * H_) ? W1[(size_t)k * 380 + col] : 0.f;
  int cg = col >> 4, nl = col & 15, kb = k >> 5, kl = k & 31;
  W1S[(((size_t)cg * NKF + kb) * 512) + (nl + 16 * (kl >> 3)) * 8 + (kl & 7)] = (f16)v;
}

__global__ __launch_bounds__(256)
void k_fc1(const f16* __restrict__ xqS, const f16* __restrict__ W1S,
           const float* __restrict__ b1, float* __restrict__ z1) {
  const int lane = threadIdx.x & 63, wid = threadIdx.x >> 6;
  const int ct = blockIdx.x % 6, rg = blockIdx.x / 6;
  const int rtile = rg * 4 + wid;
  const int r0 = rtile * 16;

  const f16* Abase = xqS + (size_t)rtile * NKF * 512 + lane * 8;
  const f16* Bbase = W1S + (size_t)(ct * 4) * NKF * 512 + lane * 8;

  half8 fa0, fa1, fa2, fa3;
  half8 fb0[4], fb1[4], fb2[4], fb3[4];
  f32x4 acc[4];
  #pragma unroll
  for (int cb = 0; cb < 4; cb++) { f32x4 z = {0.f, 0.f, 0.f, 0.f}; acc[cb] = z; }

#define LDA_F(d, kb)  d = *(const half8*)(Abase + (size_t)(kb) * 512)
#define LDB_F(d, kb)  { _Pragma("unroll") for (int cb = 0; cb < 4; cb++) \
    d[cb] = *(const half8*)(Bbase + ((size_t)cb * NKF + (kb)) * 512); }
#define MMA_F(fa, fb) { _Pragma("unroll") for (int cb = 0; cb < 4; cb++) \
    acc[cb] = __builtin_amdgcn_mfma_f32_16x16x32_f16(fa, fb[cb], acc[cb], 0, 0, 0); }

  LDA_F(fa0, 0); LDB_F(fb0, 0);
  LDA_F(fa1, 1); LDB_F(fb1, 1);
  LDA_F(fa2, 2); LDB_F(fb2, 2);
  for (int base = 0; base < 116; base += 4) {
    LDA_F(fa3, base + 3); LDB_F(fb3, base + 3);
    MMA_F(fa0, fb0);
    LDA_F(fa0, base + 4); LDB_F(fb0, base + 4);
    MMA_F(fa1, fb1);
    LDA_F(fa1, base + 5); LDB_F(fb1, base + 5);
    MMA_F(fa2, fb2);
    LDA_F(fa2, base + 6); LDB_F(fb2, base + 6);
    MMA_F(fa3, fb3);
  }
  LDA_F(fa3, 119); LDB_F(fb3, 119);
  MMA_F(fa0, fb0);   // 116
  MMA_F(fa1, fb1);   // 117
  MMA_F(fa2, fb2);   // 118
  MMA_F(fa3, fb3);   // 119
#undef LDA_F
#undef LDB_F
#undef MMA_F

  const int q4 = lane >> 4, c16 = lane & 15;
  #pragma unroll
  for (int cb = 0; cb < 4; cb++)
    #pragma unroll
    for (int q = 0; q < 4; q++) {
      int row = r0 + q4 * 4 + q;
      int col = ct * 64 + cb * 16 + c16;
      float bias = (col < 380) ? b1[col] : 0.f;
      z1[(size_t)row * FCN + col] = acc[cb][q] + bias;
    }
}

__global__ void k_fc2(const float* __restrict__ z1, const float* __restrict__ g2,
                      const float* __restrict__ be2, const float* __restrict__ mu2,
                      const float* __restrict__ var2, const float* __restrict__ W2,
                      const float* __restrict__ b2, float* __restrict__ out) {
  int s = threadIdx.x;
  float a = 0.f;
  for (int jj = 0; jj < 380; jj++) {
    float v = z1[(size_t)s * FCN + jj];
    float lr = v < 0.f ? 0.3f * v : v;
    float q = (lr - mu2[jj]) * rsqrtf(var2[jj] + 1e-3f) * g2[jj] + be2[jj];
    a += q * W2[jj];
  }
  out[s] = a + b2[0];
}

// ---------------- host ----------------

extern "C" void kernel_launch(void* const* d_in, const int* in_sizes, int n_in,
                              void* d_out, int out_size, void* d_ws, size_t ws_size,
                              hipStream_t stream) {
  const int*   epix  = (const int*)d_in[0];
  const int*   lx    = (const int*)d_in[1];
  const int*   rx    = (const int*)d_in[2];
  const int*   totx  = (const int*)d_in[3];
  const float* embed = (const float*)d_in[4];
  const float* wx    = (const float*)d_in[5];
  const float* wh    = (const float*)d_in[6];
  const float* wmx   = (const float*)d_in[7];
  const float* wmh   = (const float*)d_in[8];
  const float* bb    = (const float*)d_in[9];
  const float* gx    = (const float*)d_in[10];
  const float* gh    = (const float*)d_in[11];
  const float* gmx   = (const float*)d_in[12];
  const float* gmh   = (const float*)d_in[13];
  const float* bn1g  = (const float*)d_in[14];
  const float* bn1b  = (const float*)d_in[15];
  const float* bn1m  = (const float*)d_in[16];
  const float* bn1v  = (const float*)d_in[17];
  const float* W1    = (const float*)d_in[18];
  const float* b1    = (const float*)d_in[19];
  const float* bn2g  = (const float*)d_in[20];
  const float* bn2b  = (const float*)d_in[21];
  const float* bn2m  = (const float*)d_in[22];
  const float* bn2v  = (const float*)d_in[23];
  const float* W2    = (const float*)d_in[24];
  const float* b2v   = (const float*)d_in[25];

  char* base = (char*)d_ws;
  size_t off = 0;
  auto alloc = [&](size_t n) { char* p = base + off; off = (off + n + 255) & ~(size_t)255; return p; };

  f16*   WmhS   = (f16*)  alloc((size_t)120 * NKA * 512 * 2);
  f16*   WhS    = (f16*)  alloc((size_t)119 * 4 * NKB * 512 * 2);
  f16*   wmxT   = (f16*)  alloc((size_t)HP * 32 * 2);
  f16*   xe16   = (f16*)  alloc((size_t)TT * NR * 32 * 2);
  f16*   mR     = (f16*)  alloc((size_t)RING * MSLOT * 2);
  f16*   hR     = (f16*)  alloc((size_t)RING * HSLOT * 2);
  float* selH   = (float*)alloc((size_t)NR * HP * 4);
  int*   sel    = (int*)  alloc((size_t)NR * 4);
  int*   bar    = (int*)  alloc(256);
  float* inv_wh = (float*)alloc(7600 * 4);
  float* inv_wx = (float*)alloc(7600 * 4);
  float* inv_wmh= (float*)alloc(1900 * 4);
  float* inv_wmx= (float*)alloc(1900 * 4);
  f16*   xqS    = (f16*)  alloc((size_t)16 * NKF * 512 * 2);
  f16*   W1S    = (f16*)  alloc((size_t)24 * NKF * 512 * 2);
  float* z1     = (float*)alloc((size_t)256 * FCN * 4);
  (void)in_sizes; (void)n_in; (void)out_size; (void)ws_size;

  hipLaunchKernelGGL(k_norms, dim3(75), dim3(256), 0, stream,
                     wh, wx, wmh, wmx, gh, gx, gmh, gmx, inv_wh, inv_wx, inv_wmh, inv_wmx);
  hipLaunchKernelGGL(k_wmhS, dim3((1920 * 1920 + 255) / 256), dim3(256), 0, stream,
                     wmh, inv_wmh, WmhS);
  hipLaunchKernelGGL(k_whS, dim3((7600 * 1952 + 255) / 256), dim3(256), 0, stream,
                     wh, wx, bb, inv_wh, inv_wx, WhS);
  hipLaunchKernelGGL(k_wmxT, dim3((HP * 32 + 255) / 256), dim3(256), 0, stream,
                     wmx, inv_wmx, wmxT);
  hipLaunchKernelGGL(k_lens, dim3(1), dim3(256), 0, stream, epix, lx, rx, sel);
  hipLaunchKernelGGL(k_init, dim3((NR * HP + 255) / 256), dim3(256), 0, stream, hR, bar);
  hipLaunchKernelGGL(k_xe16, dim3((TT * NR + 255) / 256), dim3(256), 0, stream,
                     totx, epix, embed, xe16);

  hipLaunchKernelGGL(k_recur, dim3(NBLK), dim3(256), 0, stream,
                     WmhS, WhS, xe16, wmxT, mR, hR, selH, sel, bar);

  hipLaunchKernelGGL(k_xqS, dim3((256 * 3840 + 255) / 256), dim3(256), 0, stream,
                     selH, bn1g, bn1b, bn1m, bn1v, xqS);
  hipLaunchKernelGGL(k_w1S, dim3((384 * 3840 + 255) / 256), dim3(256), 0, stream, W1, W1S);
  hipLaunchKernelGGL(k_fc1, dim3(24), dim3(256), 0, stream, xqS, W1S, b1, z1);
  hipLaunchKernelGGL(k_fc2, dim3(1), dim3(256), 0, stream,
                     z1, bn2g, bn2b, bn2m, bn2v, W2, b2v, (float*)d_out);
}